// Round 4
// baseline (287.675 us; speedup 1.0000x reference)
//
#include <hip/hip_runtime.h>
#include <hip/hip_bf16.h>

// B=4, N=2048, F=512, INTERNAL=256. adj int32. Inputs f32 (runtime-detected, bf16 fallback).
// Outputs f32: [gelu 4*2048*512 | attention 4*2048*2048].

#define B_ 4
#define N_ 2048
#define F_ 512
#define ALPHA_ 0.2f
#define NEG_INF_ -9000000000000000.0f
#define EPS_LN_ 1e-5f

typedef __attribute__((ext_vector_type(8))) short bf16x8;
typedef __attribute__((ext_vector_type(4))) float f32x4;

// ---- workspace layout (bytes); overlays: Wht over hbf (dead after gemm1), HP over Wh ----
#define HBF_OFF   0           // bf16 [8192][512]  (8388608)
#define WHT_OFF   0           // bf16 [4][512][2048] overlay
#define WT_OFF    8388608     // bf16 [512][512]   (524288)
#define WH_OFF    8912896     // f32  [8192][512]  (16777216)
#define HP_OFF    8912896     // f32 overlay
#define ATTBF_OFF 25690112    // bf16 [4][2048][2048] (33554432)
#define EL_OFF    59244544    // f32  [4][8192]
#define SC_OFF    59375616    // f32  [16]
#define FLAG_OFF  59375680    // int
#define CANON_OFF 59375744    // f32  [3152]

#define C_ALP 0
#define C_ARP 256
#define C_ALN 512
#define C_ARN 768
#define C_GAM 2128
#define C_BET 2640

__device__ __forceinline__ float bf_as_f32(unsigned short u) {
    return __uint_as_float(((unsigned)u) << 16);
}
__device__ __forceinline__ float ldf(const void* p, long i, int isf32) {
    return isf32 ? ((const float*)p)[i] : bf_as_f32(((const unsigned short*)p)[i]);
}
__device__ __forceinline__ short f2bf(float f) {
    __hip_bfloat16 t = __float2bfloat16(f);
    return *reinterpret_cast<short*>(&t);
}

#define GLL16(g, l) __builtin_amdgcn_global_load_lds( \
    (const __attribute__((address_space(1))) void*)(g), \
    (__attribute__((address_space(3))) void*)(l), 16, 0, 0)

// ---------- k_prep: dtype detect + small-vector canon + scalars (1 block) ----------
__global__ void k_prep(const unsigned short* __restrict__ hraw,
                       const void* alp, const void* arp, const void* aln, const void* arn,
                       const void* rel, const void* arelp, const void* areln,
                       const void* ll1, const void* lr1, const void* ll2, const void* lr2,
                       const void* gam, const void* bet,
                       int* __restrict__ flag, float* __restrict__ canon, float* __restrict__ sc) {
    __shared__ float wmax[4];
    __shared__ int s_fl;
    int tid = threadIdx.x, lane = tid & 63, wid = tid >> 6;
    float mx = 0.f;
    for (int i = tid; i < 8192; i += 256) {
        float v = fabsf(bf_as_f32(hraw[i]));
        if (v == v && v > mx) mx = v;
    }
    for (int off = 32; off; off >>= 1) mx = fmaxf(mx, __shfl_down(mx, off));
    if (lane == 0) wmax[wid] = mx;
    __syncthreads();
    if (tid == 0) {
        float m = fmaxf(fmaxf(wmax[0], wmax[1]), fmaxf(wmax[2], wmax[3]));
        int f = (m > 1e10f) ? 1 : 0;
        s_fl = f; flag[0] = f;
    }
    __syncthreads();
    int fl = s_fl;
    canon[C_ALP + tid] = ldf(alp, tid, fl);
    canon[C_ARP + tid] = ldf(arp, tid, fl);
    canon[C_ALN + tid] = ldf(aln, tid, fl);
    canon[C_ARN + tid] = ldf(arn, tid, fl);
    canon[C_GAM + tid] = ldf(gam, tid, fl);
    canon[C_GAM + 256 + tid] = ldf(gam, 256 + tid, fl);
    canon[C_BET + tid] = ldf(bet, tid, fl);
    canon[C_BET + 256 + tid] = ldf(bet, 256 + tid, fl);
    if (wid == 0) {
        float s1 = 0.f, s2 = 0.f;
        for (int k = lane; k < 256; k += 64) {
            s1 += ldf(ll1, k, fl) * ldf(lr1, k, fl);
            s2 += ldf(ll2, k, fl) * ldf(lr2, k, fl);
        }
        for (int off = 32; off; off >>= 1) { s1 += __shfl_down(s1, off); s2 += __shfl_down(s2, off); }
        if (lane == 0) {
            float lam_init = 0.8f - 0.6f * expf(-0.3f);
            sc[0] = expf(s1) - expf(s2) + lam_init;
        }
    } else if (wid == 1 && lane < 6) {
        float p = 0.f, n = 0.f;
        for (int d = 0; d < 10; ++d) {
            float rv = ldf(rel, lane * 10 + d, fl);
            p += rv * ldf(arelp, d, fl);
            n += rv * ldf(areln, d, fl);
        }
        sc[1 + lane] = p;
        sc[7 + lane] = n;
    }
}

// ---------- k_conv_h8: h -> bf16, 8 elements/thread ----------
__global__ __launch_bounds__(256) void k_conv_h8(const void* __restrict__ h, const int* __restrict__ flag,
                                                 short* __restrict__ hbf) {
    int fl = flag[0];
    int i = (blockIdx.x * 256 + threadIdx.x) * 8;   // 4194304 elements
    bf16x8 v;
    if (fl) {
        const float4* p = (const float4*)((const float*)h + i);
        float4 a = p[0], b = p[1];
        v[0] = f2bf(a.x); v[1] = f2bf(a.y); v[2] = f2bf(a.z); v[3] = f2bf(a.w);
        v[4] = f2bf(b.x); v[5] = f2bf(b.y); v[6] = f2bf(b.z); v[7] = f2bf(b.w);
    } else {
        v = *(const bf16x8*)((const short*)h + i);
    }
    *(bf16x8*)(hbf + i) = v;
}

// ---------- k_transW: W[k][o] (f32/bf16) -> Wt[o][k] bf16, LDS 32x32 tiles ----------
__global__ __launch_bounds__(256) void k_transW(const void* __restrict__ W, const int* __restrict__ flag,
                                                __hip_bfloat16* __restrict__ Wt) {
    __shared__ float t[32][33];
    int fl = flag[0];
    int k0 = blockIdx.x * 32, o0 = blockIdx.y * 32;
    int tx = threadIdx.x & 31, ty = threadIdx.x >> 5;
#pragma unroll
    for (int r = 0; r < 4; ++r)
        t[ty + r * 8][tx] = ldf(W, (k0 + ty + r * 8) * 512 + o0 + tx, fl);
    __syncthreads();
#pragma unroll
    for (int r = 0; r < 4; ++r)
        Wt[(o0 + ty + r * 8) * 512 + k0 + tx] = __float2bfloat16(t[tx][ty + r * 8]);
}

// ---------- generic 128x128 MFMA GEMM: A[M][K] bf16, B[N][K] bf16 -> C[M][N] f32 ----------
// m97 structure: global_load_lds(16B) staging, 2 barriers/K-step, 4 waves each 64x64 out.
__global__ __launch_bounds__(256) void k_gemm128(const short* __restrict__ A, const short* __restrict__ B,
                                                 float* __restrict__ C, int K, int N,
                                                 long aBatch, long bBatch, long cBatch) {
    __shared__ short As[128 * 32];
    __shared__ short Bs[128 * 32];
    int tid = threadIdx.x, wid = tid >> 6, lane = tid & 63;
    int bm = blockIdx.x * 128, bn = blockIdx.y * 128;
    int bz = blockIdx.z;
    const short* Ab = A + bz * aBatch + (long)bm * K;
    const short* Bb = B + bz * bBatch + (long)bn * K;
    f32x4 acc[4][4] = {};
    int wr = (wid >> 1) * 64, wc = (wid & 1) * 64;
    int c0 = wid * 64 + lane, c1 = c0 + 256;
    int r0 = c0 >> 2, q0 = (c0 & 3) * 8;
    int r1 = c1 >> 2, q1 = (c1 & 3) * 8;
    int l15 = lane & 15, kh = (lane >> 4) * 8;
    for (int k0 = 0; k0 < K; k0 += 32) {
        __syncthreads();
        GLL16(Ab + (long)r0 * K + k0 + q0, As + c0 * 8);
        GLL16(Ab + (long)r1 * K + k0 + q1, As + c1 * 8);
        GLL16(Bb + (long)r0 * K + k0 + q0, Bs + c0 * 8);
        GLL16(Bb + (long)r1 * K + k0 + q1, Bs + c1 * 8);
        __syncthreads();   // compiler drains vmcnt before s_barrier -> LDS valid
        bf16x8 af[4], bq[4];
#pragma unroll
        for (int m = 0; m < 4; ++m) af[m] = *(const bf16x8*)&As[(wr + m * 16 + l15) * 32 + kh];
#pragma unroll
        for (int n = 0; n < 4; ++n) bq[n] = *(const bf16x8*)&Bs[(wc + n * 16 + l15) * 32 + kh];
#pragma unroll
        for (int m = 0; m < 4; ++m)
#pragma unroll
            for (int n = 0; n < 4; ++n)
                acc[m][n] = __builtin_amdgcn_mfma_f32_16x16x32_bf16(af[m], bq[n], acc[m][n], 0, 0, 0);
    }
    int rg = (lane >> 4) * 4;
#pragma unroll
    for (int m = 0; m < 4; ++m)
#pragma unroll
        for (int n = 0; n < 4; ++n)
#pragma unroll
            for (int r = 0; r < 4; ++r) {
                int row = bm + wr + m * 16 + rg + r;
                int col = bn + wc + n * 16 + l15;
                C[bz * cBatch + (long)row * N + col] = acc[m][n][r];
            }
}

// ---------- transpose Wh -> Wht[b][o][j] bf16 ----------
__global__ __launch_bounds__(256) void k_transWh(const float* __restrict__ Wh, __hip_bfloat16* __restrict__ Wht) {
    __shared__ float t[32][33];
    int b = blockIdx.z;
    int o0 = blockIdx.x * 32, j0 = blockIdx.y * 32;
    int tx = threadIdx.x & 31, ty = threadIdx.x >> 5;
#pragma unroll
    for (int r = 0; r < 4; ++r)
        t[ty + r * 8][tx] = Wh[(b * 2048 + j0 + ty + r * 8) * 512 + o0 + tx];
    __syncthreads();
#pragma unroll
    for (int r = 0; r < 4; ++r)
        Wht[((long)b * 512 + o0 + ty + r * 8) * 2048 + j0 + tx] = __float2bfloat16(t[tx][ty + r * 8]);
}

// ---------- per-row e dots ----------
__global__ __launch_bounds__(256) void k_edots(const float* __restrict__ Wh, const float* __restrict__ canon,
                                               float* __restrict__ el) {
    int wid = threadIdx.x >> 6, lane = threadIdx.x & 63;
    int m = blockIdx.x * 4 + wid;
    float selp = 0.f, serp = 0.f, seln = 0.f, sern = 0.f;
#pragma unroll
    for (int t = 0; t < 4; ++t) {
        int k = t * 64 + lane;
        float wp = Wh[m * 512 + k];
        float wn = Wh[m * 512 + 256 + k];
        selp += wp * canon[C_ALP + k];
        serp += wp * canon[C_ARP + k];
        seln += wn * canon[C_ALN + k];
        sern += wn * canon[C_ARN + k];
    }
    for (int off = 32; off; off >>= 1) {
        selp += __shfl_down(selp, off); serp += __shfl_down(serp, off);
        seln += __shfl_down(seln, off); sern += __shfl_down(sern, off);
    }
    if (lane == 0) {
        el[m] = selp; el[8192 + m] = serp; el[16384 + m] = seln; el[24576 + m] = sern;
    }
}

// ---------- attention rows: dual softmax (fast exp); f32 att -> d_out, bf16 att -> ws ----------
__global__ __launch_bounds__(256) void k_attn(const int* __restrict__ adj,
                                              const float* __restrict__ el, const float* __restrict__ sc,
                                              float* __restrict__ att_f32,
                                              __hip_bfloat16* __restrict__ att_bf) {
    __shared__ float s_rp[6], s_rn[6], s_lam[1];
    __shared__ float rmp[4], rmn[4], rsp[4], rsn[4];
    int tid = threadIdx.x, lane = tid & 63, wid = tid >> 6;
    if (tid < 6) { s_rp[tid] = sc[1 + tid]; s_rn[tid] = sc[7 + tid]; }
    if (tid == 6) s_lam[0] = sc[0];
    int m = blockIdx.x, b = m >> 11;
    float elp = el[m], eln = el[16384 + m];
    const float* erp = el + 8192 + b * 2048;
    const float* ern = el + 24576 + b * 2048;
    const int* adjr = adj + (long)m * 2048;
    __syncthreads();
    float sp[8], sn[8];
    float mp = NEG_INF_, mn = NEG_INF_;
#pragma unroll
    for (int t = 0; t < 8; ++t) {
        int j = t * 256 + tid;
        int a = adjr[j];
        float ep = elp + erp[j] + s_rp[a];
        float en = eln + ern[j] + s_rn[a];
        ep = ep >= 0.f ? ep : ALPHA_ * ep;
        en = en >= 0.f ? en : ALPHA_ * en;
        sp[t] = a > 0 ? ep : NEG_INF_;
        sn[t] = a > 0 ? en : NEG_INF_;
        mp = fmaxf(mp, sp[t]); mn = fmaxf(mn, sn[t]);
    }
    for (int off = 32; off; off >>= 1) { mp = fmaxf(mp, __shfl_down(mp, off)); mn = fmaxf(mn, __shfl_down(mn, off)); }
    if (lane == 0) { rmp[wid] = mp; rmn[wid] = mn; }
    __syncthreads();
    mp = fmaxf(fmaxf(rmp[0], rmp[1]), fmaxf(rmp[2], rmp[3]));
    mn = fmaxf(fmaxf(rmn[0], rmn[1]), fmaxf(rmn[2], rmn[3]));
    float sump = 0.f, sumn = 0.f;
#pragma unroll
    for (int t = 0; t < 8; ++t) {
        sp[t] = __expf(sp[t] - mp);    // native v_exp; masked -> 0; all-masked row -> uniform
        sn[t] = __expf(sn[t] - mn);
        sump += sp[t]; sumn += sn[t];
    }
    for (int off = 32; off; off >>= 1) { sump += __shfl_down(sump, off); sumn += __shfl_down(sumn, off); }
    if (lane == 0) { rsp[wid] = sump; rsn[wid] = sumn; }
    __syncthreads();
    sump = rsp[0] + rsp[1] + rsp[2] + rsp[3];
    sumn = rsn[0] + rsn[1] + rsn[2] + rsn[3];
    float ip = 1.0f / sump, inn = 1.0f / sumn;
    float lam = s_lam[0];
#pragma unroll
    for (int t = 0; t < 8; ++t) {
        float v = sp[t] * ip - lam * sn[t] * inn;
        long idx = (long)m * 2048 + t * 256 + tid;
        att_f32[idx] = v;
        att_bf[idx] = __float2bfloat16(v);
    }
}

// ---------- LayerNorm + gamma/beta + *(1-lam_init) + exact GELU -> f32 ----------
__global__ __launch_bounds__(256) void k_lngelu(const float* __restrict__ HP, const float* __restrict__ canon,
                                                float* __restrict__ out) {
    int wid = threadIdx.x >> 6, lane = threadIdx.x & 63;
    int m = blockIdx.x * 4 + wid;
    float x[8]; float s = 0.f, ss = 0.f;
#pragma unroll
    for (int t = 0; t < 8; ++t) {
        x[t] = HP[m * 512 + t * 64 + lane];
        s += x[t]; ss += x[t] * x[t];
    }
    for (int off = 32; off; off >>= 1) { s += __shfl_xor(s, off); ss += __shfl_xor(ss, off); }
    float mu = s * (1.0f / 512.0f);
    float var = ss * (1.0f / 512.0f) - mu * mu;
    float inv = rsqrtf(fmaxf(var, 0.0f) + EPS_LN_);
    float scale = 1.0f - (0.8f - 0.6f * expf(-0.3f));
#pragma unroll
    for (int t = 0; t < 8; ++t) {
        int k = t * 64 + lane;
        float y = (x[t] - mu) * inv * canon[C_GAM + k] + canon[C_BET + k];
        y *= scale;
        float g = 0.5f * y * (1.0f + erff(y * 0.70710678118654752f));
        out[m * 512 + k] = g;
    }
}

extern "C" void kernel_launch(void* const* d_in, const int* in_sizes, int n_in,
                              void* d_out, int out_size, void* d_ws, size_t ws_size,
                              hipStream_t stream) {
    const void* h   = d_in[0];
    const int*  adj = (const int*)d_in[1];
    const void* W   = d_in[2];

    char* ws = (char*)d_ws;
    short*          hbf   = (short*)(ws + HBF_OFF);
    __hip_bfloat16* Wt    = (__hip_bfloat16*)(ws + WT_OFF);
    float*          Wh    = (float*)(ws + WH_OFF);
    __hip_bfloat16* Wht   = (__hip_bfloat16*)(ws + WHT_OFF);
    __hip_bfloat16* attbf = (__hip_bfloat16*)(ws + ATTBF_OFF);
    float*          el    = (float*)(ws + EL_OFF);
    float*          sc    = (float*)(ws + SC_OFF);
    int*            flg   = (int*)(ws + FLAG_OFF);
    float*          can   = (float*)(ws + CANON_OFF);
    float*          HP    = (float*)(ws + HP_OFF);

    float* out_gelu = (float*)d_out;
    float* out_att  = out_gelu + (size_t)B_ * N_ * F_;

    k_prep<<<1, 256, 0, stream>>>((const unsigned short*)h,
                                  d_in[3], d_in[4], d_in[5], d_in[6], d_in[7], d_in[8], d_in[9],
                                  d_in[10], d_in[11], d_in[12], d_in[13], d_in[14], d_in[15],
                                  flg, can, sc);
    k_conv_h8<<<2048, 256, 0, stream>>>(h, flg, hbf);
    k_transW<<<dim3(16, 16), 256, 0, stream>>>(W, flg, Wt);
    // Wh = h @ W : M=8192 K=512 N=512
    k_gemm128<<<dim3(64, 4, 1), 256, 0, stream>>>(hbf, (const short*)Wt, Wh, 512, 512, 0, 0, 0);
    k_transWh<<<dim3(16, 64, 4), 256, 0, stream>>>(Wh, Wht);   // overwrites hbf (dead)
    k_edots<<<2048, 256, 0, stream>>>(Wh, can, el);
    k_attn<<<8192, 256, 0, stream>>>(adj, el, sc, out_att, attbf);
    // h_prime = att @ Wh : per batch M=2048 K=2048 N=512
    k_gemm128<<<dim3(16, 4, 4), 256, 0, stream>>>((const short*)attbf, (const short*)Wht, HP, 2048, 512,
                                                  2048L * 2048, 512L * 2048, 2048L * 512);  // overwrites Wh (dead)
    k_lngelu<<<2048, 256, 0, stream>>>(HP, can, out_gelu);
}

// Round 5
// 276.227 us; speedup vs baseline: 1.0414x; 1.0414x over previous
//
#include <hip/hip_runtime.h>
#include <hip/hip_bf16.h>

// B=4, N=2048, F=512, INTERNAL=256. adj int32. Inputs f32 (runtime-detected, bf16 fallback).
// Outputs f32: [gelu 4*2048*512 | attention 4*2048*2048].

#define B_ 4
#define N_ 2048
#define F_ 512
#define ALPHA_ 0.2f
#define NEG_INF_ -9000000000000000.0f
#define EPS_LN_ 1e-5f

typedef __attribute__((ext_vector_type(8))) short bf16x8;
typedef __attribute__((ext_vector_type(4))) short bf16x4;
typedef __attribute__((ext_vector_type(4))) float f32x4;

// ---- workspace layout (bytes). Lifetimes:
//  hbf: conv->gemmWh | Wt: transW->gemmWh | el: conv->attn | Wht: gemmWh->hprime
//  attbf: attn->hprime | HP: hprime->lngelu (overlays hbf+Wt+el, all dead by then)
#define HBF_OFF   0           // bf16 [8192][512]   (8388608)
#define WT_OFF    8388608     // bf16 [512][512]    (524288)
#define EL_OFF    8912896     // f32  [4][8192]     (131072)
#define HP_OFF    0           // f32  [8192][512]   (16777216) overlay
#define WHT_OFF   16777216    // bf16 [4][512][2048](8388608)
#define ATTBF_OFF 25165824    // bf16 [4][2048][2048](33554432) -> ends 58720256
#define CANON_OFF 58720256    // f32 [3152]
#define SC_OFF    58732864    // f32 [16]
#define FLAG_OFF  58732928    // int
#define V_OFF     58736640    // f32 [4][512]  (8192)
// peak ~58.75 MB (known-good ws >= 59.37 MB)

#define C_ALP 0
#define C_ARP 256
#define C_ALN 512
#define C_ARN 768
#define C_GAM 2128
#define C_BET 2640

__device__ __forceinline__ float bf_as_f32(unsigned short u) {
    return __uint_as_float(((unsigned)u) << 16);
}
__device__ __forceinline__ float ldf(const void* p, long i, int isf32) {
    return isf32 ? ((const float*)p)[i] : bf_as_f32(((const unsigned short*)p)[i]);
}
__device__ __forceinline__ short f2bf(float f) {
    __hip_bfloat16 t = __float2bfloat16(f);
    return *reinterpret_cast<short*>(&t);
}

#define GLL16(g, l) __builtin_amdgcn_global_load_lds( \
    (const __attribute__((address_space(1))) void*)(g), \
    (__attribute__((address_space(3))) void*)(l), 16, 0, 0)

// ---------- k_prep: dtype detect + canon + scalars + zero v (1 block) ----------
__global__ void k_prep(const unsigned short* __restrict__ hraw,
                       const void* alp, const void* arp, const void* aln, const void* arn,
                       const void* rel, const void* arelp, const void* areln,
                       const void* ll1, const void* lr1, const void* ll2, const void* lr2,
                       const void* gam, const void* bet,
                       int* __restrict__ flag, float* __restrict__ canon, float* __restrict__ sc,
                       float* __restrict__ v) {
    __shared__ float wmax[4];
    __shared__ int s_fl;
    int tid = threadIdx.x, lane = tid & 63, wid = tid >> 6;
    float mx = 0.f;
    for (int i = tid; i < 8192; i += 256) {
        float x = fabsf(bf_as_f32(hraw[i]));
        if (x == x && x > mx) mx = x;
    }
    for (int off = 32; off; off >>= 1) mx = fmaxf(mx, __shfl_down(mx, off));
    if (lane == 0) wmax[wid] = mx;
    __syncthreads();
    if (tid == 0) {
        float m = fmaxf(fmaxf(wmax[0], wmax[1]), fmaxf(wmax[2], wmax[3]));
        int f = (m > 1e10f) ? 1 : 0;
        s_fl = f; flag[0] = f;
    }
    __syncthreads();
    int fl = s_fl;
    for (int i = tid; i < 2048; i += 256) v[i] = 0.f;
    canon[C_ALP + tid] = ldf(alp, tid, fl);
    canon[C_ARP + tid] = ldf(arp, tid, fl);
    canon[C_ALN + tid] = ldf(aln, tid, fl);
    canon[C_ARN + tid] = ldf(arn, tid, fl);
    canon[C_GAM + tid] = ldf(gam, tid, fl);
    canon[C_GAM + 256 + tid] = ldf(gam, 256 + tid, fl);
    canon[C_BET + tid] = ldf(bet, tid, fl);
    canon[C_BET + 256 + tid] = ldf(bet, 256 + tid, fl);
    if (wid == 0) {
        float s1 = 0.f, s2 = 0.f;
        for (int k = lane; k < 256; k += 64) {
            s1 += ldf(ll1, k, fl) * ldf(lr1, k, fl);
            s2 += ldf(ll2, k, fl) * ldf(lr2, k, fl);
        }
        for (int off = 32; off; off >>= 1) { s1 += __shfl_down(s1, off); s2 += __shfl_down(s2, off); }
        if (lane == 0) {
            float lam_init = 0.8f - 0.6f * expf(-0.3f);
            sc[0] = expf(s1) - expf(s2) + lam_init;
        }
    } else if (wid == 1 && lane < 6) {
        float p = 0.f, n = 0.f;
        for (int d = 0; d < 10; ++d) {
            float rv = ldf(rel, lane * 10 + d, fl);
            p += rv * ldf(arelp, d, fl);
            n += rv * ldf(areln, d, fl);
        }
        sc[1 + lane] = p;
        sc[7 + lane] = n;
    }
}

// ---------- k_transW: W[k][o] -> Wt[o][k] bf16 + v[4][512] = W@a partial dots ----------
__global__ __launch_bounds__(256) void k_transW(const void* __restrict__ W, const int* __restrict__ flag,
                                                __hip_bfloat16* __restrict__ Wt,
                                                const float* __restrict__ canon, float* __restrict__ v) {
    __shared__ float t[32][33];
    int fl = flag[0];
    int k0 = blockIdx.x * 32, o0 = blockIdx.y * 32;
    int tx = threadIdx.x & 31, ty = threadIdx.x >> 5;
#pragma unroll
    for (int r = 0; r < 4; ++r)
        t[ty + r * 8][tx] = ldf(W, (k0 + ty + r * 8) * 512 + o0 + tx, fl);
    __syncthreads();
#pragma unroll
    for (int r = 0; r < 4; ++r)
        Wt[(o0 + ty + r * 8) * 512 + k0 + tx] = __float2bfloat16(t[tx][ty + r * 8]);
    // v contribution: v[vec][k] += sum_o W[k][o]*a[o]
    int kl = threadIdx.x >> 3;          // 0..31
    int seg = threadIdx.x & 7;          // 0..7 -> o range seg*4..seg*4+3
    int neg = o0 >= 256;
    const float* aL = canon + (neg ? C_ALN : C_ALP) + (o0 & 255);
    const float* aR = canon + (neg ? C_ARN : C_ARP) + (o0 & 255);
    float s0 = 0.f, s1 = 0.f;
#pragma unroll
    for (int e = 0; e < 4; ++e) {
        float w = t[kl][seg * 4 + e];
        s0 += w * aL[seg * 4 + e];
        s1 += w * aR[seg * 4 + e];
    }
    s0 += __shfl_xor(s0, 1); s0 += __shfl_xor(s0, 2); s0 += __shfl_xor(s0, 4);
    s1 += __shfl_xor(s1, 1); s1 += __shfl_xor(s1, 2); s1 += __shfl_xor(s1, 4);
    if (seg == 0) {
        int vb = neg ? 2 : 0;
        atomicAdd(&v[(vb + 0) * 512 + k0 + kl], s0);
        atomicAdd(&v[(vb + 1) * 512 + k0 + kl], s1);
    }
}

// ---------- k_conv_h8: h -> bf16 (8/thread) + fused el row-dots (wave = 1 row) ----------
__global__ __launch_bounds__(256) void k_conv_h8(const void* __restrict__ h, const int* __restrict__ flag,
                                                 short* __restrict__ hbf, const float* __restrict__ v,
                                                 float* __restrict__ el) {
    int fl = flag[0];
    int tid = threadIdx.x, lane = tid & 63;
    long i = ((long)blockIdx.x * 256 + tid) * 8;
    int row = (int)(i >> 9);
    float f[8];
    if (fl) {
        const float4* p = (const float4*)((const float*)h + i);
        float4 a = p[0], b = p[1];
        f[0] = a.x; f[1] = a.y; f[2] = a.z; f[3] = a.w;
        f[4] = b.x; f[5] = b.y; f[6] = b.z; f[7] = b.w;
    } else {
        bf16x8 x = *(const bf16x8*)((const short*)h + i);
#pragma unroll
        for (int e = 0; e < 8; ++e) f[e] = bf_as_f32((unsigned short)x[e]);
    }
    bf16x8 vv;
#pragma unroll
    for (int e = 0; e < 8; ++e) vv[e] = f2bf(f[e]);
    *(bf16x8*)(hbf + i) = vv;
    // el dots: k = lane*8 + e
    const float* v0 = v + 0 * 512 + lane * 8;
    const float* v1 = v + 1 * 512 + lane * 8;
    const float* v2 = v + 2 * 512 + lane * 8;
    const float* v3 = v + 3 * 512 + lane * 8;
    float slp = 0.f, srp = 0.f, sln = 0.f, srn = 0.f;
#pragma unroll
    for (int e = 0; e < 8; ++e) {
        slp += f[e] * v0[e]; srp += f[e] * v1[e];
        sln += f[e] * v2[e]; srn += f[e] * v3[e];
    }
    for (int off = 32; off; off >>= 1) {
        slp += __shfl_xor(slp, off); srp += __shfl_xor(srp, off);
        sln += __shfl_xor(sln, off); srn += __shfl_xor(srn, off);
    }
    if (lane == 0) {
        el[row] = slp; el[8192 + row] = srp; el[16384 + row] = sln; el[24576 + row] = srn;
    }
}

// ---------- generic MFMA GEMM: BM=128 BN=64 BK=64, 4 waves (64x32 each), XOR-swizzled LDS ----
// TRANS_OUT=0: C f32 [M][N] row-major.  TRANS_OUT=1: C bf16 Wht[b][o][j] (transposed store).
template<int TRANS_OUT>
__global__ __launch_bounds__(256) void k_gemm(const short* __restrict__ A, const short* __restrict__ B,
                                              void* __restrict__ Cout, int K, int N,
                                              long aBatch, long bBatch, long cBatch) {
    __shared__ short SM[12288];         // As 128x64 (16KB) + Bs 64x64 (8KB)
    short* As = SM;
    short* Bs = SM + 8192;
    int tid = threadIdx.x, wid = tid >> 6, lane = tid & 63;
    int bm = blockIdx.x * 128, bn = blockIdx.y * 64, bz = blockIdx.z;
    const short* Ab = A + bz * aBatch + (long)bm * K;
    const short* Bb = B + bz * bBatch + (long)bn * K;
    f32x4 acc[4][2] = {};
    int wr = (wid >> 1) * 64, wc = (wid & 1) * 32;
    int l15 = lane & 15, lhi = lane >> 4;
    for (int k0 = 0; k0 < K; k0 += 64) {
        __syncthreads();
#pragma unroll
        for (int j = 0; j < 4; ++j) {       // A: 1024 16B-chunks, swizzled source (rule 21)
            int q = tid + j * 256;
            int row = q >> 3, c = (q & 7) ^ (row & 7);
            GLL16(Ab + (long)row * K + k0 + c * 8, As + q * 8);
        }
#pragma unroll
        for (int j = 0; j < 2; ++j) {       // B: 512 chunks
            int q = tid + j * 256;
            int row = q >> 3, c = (q & 7) ^ (row & 7);
            GLL16(Bb + (long)row * K + k0 + c * 8, Bs + q * 8);
        }
        __syncthreads();                    // compiler drains vmcnt before barrier
#pragma unroll
        for (int ks = 0; ks < 2; ++ks) {
            bf16x8 af[4], bq[2];
#pragma unroll
            for (int m = 0; m < 4; ++m) {
                int r = wr + m * 16 + l15;
                int c = (ks * 4 + lhi) ^ (r & 7);
                af[m] = *(const bf16x8*)&As[r * 64 + c * 8];
            }
#pragma unroll
            for (int n = 0; n < 2; ++n) {
                int r = wc + n * 16 + l15;
                int c = (ks * 4 + lhi) ^ (r & 7);
                bq[n] = *(const bf16x8*)&Bs[r * 64 + c * 8];
            }
#pragma unroll
            for (int m = 0; m < 4; ++m)
#pragma unroll
                for (int n = 0; n < 2; ++n)
                    acc[m][n] = __builtin_amdgcn_mfma_f32_16x16x32_bf16(af[m], bq[n], acc[m][n], 0, 0, 0);
        }
    }
    int rg = lhi * 4;
    if (TRANS_OUT == 0) {
        float* C = (float*)Cout + bz * cBatch;
#pragma unroll
        for (int m = 0; m < 4; ++m)
#pragma unroll
            for (int n = 0; n < 2; ++n)
#pragma unroll
                for (int r = 0; r < 4; ++r)
                    C[(long)(bm + wr + m * 16 + rg + r) * N + bn + wc + n * 16 + l15] = acc[m][n][r];
    } else {
        // transposed bf16 store via LDS bounce: T[64 o][128 j], pad 136 shorts
        __syncthreads();
        short* T = SM;
#pragma unroll
        for (int m = 0; m < 4; ++m)
#pragma unroll
            for (int n = 0; n < 2; ++n) {
                bf16x4 p;
#pragma unroll
                for (int r = 0; r < 4; ++r) p[r] = f2bf(acc[m][n][r]);
                int o = wc + n * 16 + l15;
                int jj = wr + m * 16 + rg;
                *(bf16x4*)&T[o * 136 + jj] = p;
            }
        __syncthreads();
        int b = bm >> 11, jb = bm & 2047;
        int o = tid >> 2, sg = tid & 3;
        short* Wg = (short*)Cout + ((long)b * 512 + bn + o) * 2048 + jb + sg * 32;
#pragma unroll
        for (int w2 = 0; w2 < 4; ++w2)
            *(bf16x8*)(Wg + w2 * 8) = *(bf16x8*)&T[o * 136 + sg * 32 + w2 * 8];
    }
}

// ---------- attention rows: dual softmax; f32 att -> d_out, bf16 att -> ws (vectorized) ----
__global__ __launch_bounds__(256) void k_attn(const int* __restrict__ adj,
                                              const float* __restrict__ el, const float* __restrict__ sc,
                                              float* __restrict__ att_f32,
                                              __hip_bfloat16* __restrict__ att_bf) {
    __shared__ float s_rp[8], s_rn[8], s_lam[1];
    __shared__ float rmp[4], rmn[4], rsp[4], rsn[4];
    int tid = threadIdx.x, lane = tid & 63, wid = tid >> 6;
    if (tid < 6) { s_rp[tid] = sc[1 + tid]; s_rn[tid] = sc[7 + tid]; }
    if (tid == 6) s_lam[0] = sc[0];
    int m = blockIdx.x, b = m >> 11;
    float elp = el[m], eln = el[16384 + m];
    const float* erp = el + 8192 + b * 2048;
    const float* ern = el + 24576 + b * 2048;
    const int* adjr = adj + (long)m * 2048;
    __syncthreads();
    int j0 = tid * 8;
    int4 A0 = *(const int4*)(adjr + j0), A1 = *(const int4*)(adjr + j0 + 4);
    float4 P0 = *(const float4*)(erp + j0), P1 = *(const float4*)(erp + j0 + 4);
    float4 Q0 = *(const float4*)(ern + j0), Q1 = *(const float4*)(ern + j0 + 4);
    int aa[8] = {A0.x, A0.y, A0.z, A0.w, A1.x, A1.y, A1.z, A1.w};
    float rp[8] = {P0.x, P0.y, P0.z, P0.w, P1.x, P1.y, P1.z, P1.w};
    float rn[8] = {Q0.x, Q0.y, Q0.z, Q0.w, Q1.x, Q1.y, Q1.z, Q1.w};
    float sp[8], sn[8];
    float mp = NEG_INF_, mn = NEG_INF_;
#pragma unroll
    for (int e = 0; e < 8; ++e) {
        int a = aa[e];
        float ep = elp + rp[e] + s_rp[a];
        float en = eln + rn[e] + s_rn[a];
        ep = ep >= 0.f ? ep : ALPHA_ * ep;
        en = en >= 0.f ? en : ALPHA_ * en;
        sp[e] = a > 0 ? ep : NEG_INF_;
        sn[e] = a > 0 ? en : NEG_INF_;
        mp = fmaxf(mp, sp[e]); mn = fmaxf(mn, sn[e]);
    }
    for (int off = 32; off; off >>= 1) { mp = fmaxf(mp, __shfl_down(mp, off)); mn = fmaxf(mn, __shfl_down(mn, off)); }
    if (lane == 0) { rmp[wid] = mp; rmn[wid] = mn; }
    __syncthreads();
    mp = fmaxf(fmaxf(rmp[0], rmp[1]), fmaxf(rmp[2], rmp[3]));
    mn = fmaxf(fmaxf(rmn[0], rmn[1]), fmaxf(rmn[2], rmn[3]));
    float sump = 0.f, sumn = 0.f;
#pragma unroll
    for (int e = 0; e < 8; ++e) {
        sp[e] = __expf(sp[e] - mp);     // masked -> 0; all-masked row -> uniform (matches ref)
        sn[e] = __expf(sn[e] - mn);
        sump += sp[e]; sumn += sn[e];
    }
    for (int off = 32; off; off >>= 1) { sump += __shfl_down(sump, off); sumn += __shfl_down(sumn, off); }
    if (lane == 0) { rsp[wid] = sump; rsn[wid] = sumn; }
    __syncthreads();
    sump = rsp[0] + rsp[1] + rsp[2] + rsp[3];
    sumn = rsn[0] + rsn[1] + rsn[2] + rsn[3];
    float ip = 1.0f / sump, inn = 1.0f / sumn;
    float lam = s_lam[0];
    float vout[8];
    bf16x8 vb;
#pragma unroll
    for (int e = 0; e < 8; ++e) {
        vout[e] = sp[e] * ip - lam * sn[e] * inn;
        vb[e] = f2bf(vout[e]);
    }
    float* of = att_f32 + (long)m * 2048 + j0;
    *(float4*)(of)     = make_float4(vout[0], vout[1], vout[2], vout[3]);
    *(float4*)(of + 4) = make_float4(vout[4], vout[5], vout[6], vout[7]);
    *(bf16x8*)((short*)att_bf + (long)m * 2048 + j0) = vb;
}

// ---------- LayerNorm + gamma/beta + *(1-lam_init) + exact GELU -> f32 (wave = 1 row) ----
__global__ __launch_bounds__(256) void k_lngelu(const float* __restrict__ HP, const float* __restrict__ canon,
                                                float* __restrict__ out) {
    int wid = threadIdx.x >> 6, lane = threadIdx.x & 63;
    int m = blockIdx.x * 4 + wid;
    const float* Hr = HP + (long)m * 512 + lane * 8;
    float4 x0 = *(const float4*)(Hr), x1 = *(const float4*)(Hr + 4);
    float x[8] = {x0.x, x0.y, x0.z, x0.w, x1.x, x1.y, x1.z, x1.w};
    float s = 0.f, ss = 0.f;
#pragma unroll
    for (int e = 0; e < 8; ++e) { s += x[e]; ss += x[e] * x[e]; }
    for (int off = 32; off; off >>= 1) { s += __shfl_xor(s, off); ss += __shfl_xor(ss, off); }
    float mu = s * (1.0f / 512.0f);
    float var = ss * (1.0f / 512.0f) - mu * mu;
    float inv = rsqrtf(fmaxf(var, 0.0f) + EPS_LN_);
    float scale = 1.0f - (0.8f - 0.6f * expf(-0.3f));
    const float* g8 = canon + C_GAM + lane * 8;
    const float* b8 = canon + C_BET + lane * 8;
    float o[8];
#pragma unroll
    for (int e = 0; e < 8; ++e) {
        float y = (x[e] - mu) * inv * g8[e] + b8[e];
        y *= scale;
        o[e] = 0.5f * y * (1.0f + erff(y * 0.70710678118654752f));
    }
    float* op = out + (long)m * 512 + lane * 8;
    *(float4*)(op)     = make_float4(o[0], o[1], o[2], o[3]);
    *(float4*)(op + 4) = make_float4(o[4], o[5], o[6], o[7]);
}

extern "C" void kernel_launch(void* const* d_in, const int* in_sizes, int n_in,
                              void* d_out, int out_size, void* d_ws, size_t ws_size,
                              hipStream_t stream) {
    const void* h   = d_in[0];
    const int*  adj = (const int*)d_in[1];
    const void* W   = d_in[2];

    char* ws = (char*)d_ws;
    short*          hbf   = (short*)(ws + HBF_OFF);
    __hip_bfloat16* Wt    = (__hip_bfloat16*)(ws + WT_OFF);
    float*          el    = (float*)(ws + EL_OFF);
    float*          HP    = (float*)(ws + HP_OFF);
    __hip_bfloat16* Wht   = (__hip_bfloat16*)(ws + WHT_OFF);
    __hip_bfloat16* attbf = (__hip_bfloat16*)(ws + ATTBF_OFF);
    float*          can   = (float*)(ws + CANON_OFF);
    float*          sc    = (float*)(ws + SC_OFF);
    int*            flg   = (int*)(ws + FLAG_OFF);
    float*          v     = (float*)(ws + V_OFF);

    float* out_gelu = (float*)d_out;
    float* out_att  = out_gelu + (size_t)B_ * N_ * F_;

    k_prep<<<1, 256, 0, stream>>>((const unsigned short*)h,
                                  d_in[3], d_in[4], d_in[5], d_in[6], d_in[7], d_in[8], d_in[9],
                                  d_in[10], d_in[11], d_in[12], d_in[13], d_in[14], d_in[15],
                                  flg, can, sc, v);
    k_transW<<<dim3(16, 16), 256, 0, stream>>>(W, flg, Wt, can, v);
    k_conv_h8<<<2048, 256, 0, stream>>>(h, flg, hbf, v, el);
    // Wh^T (bf16, [b][o][j]) = (hbf @ Wt^T) transposed-store : M=8192 K=512 N=512
    k_gemm<1><<<dim3(64, 8, 1), 256, 0, stream>>>(hbf, (const short*)Wt, Wht, 512, 512, 0, 0, 0);
    k_attn<<<8192, 256, 0, stream>>>(adj, el, sc, out_att, attbf);
    // h_prime = att @ Wh : per batch M=2048 K=2048 N=512 (HP overlays dead hbf/Wt/el)
    k_gemm<0><<<dim3(16, 8, 4), 256, 0, stream>>>((const short*)attbf, (const short*)Wht, HP, 2048, 512,
                                                  2048L * 2048, 512L * 2048, 2048L * 512);
    k_lngelu<<<2048, 256, 0, stream>>>(HP, can, out_gelu);
}

// Round 6
// 267.807 us; speedup vs baseline: 1.0742x; 1.0314x over previous
//
#include <hip/hip_runtime.h>
#include <hip/hip_bf16.h>

// B=4, N=2048, F=512, INTERNAL=256. adj int32. Inputs f32 (runtime-detected per-block, bf16 fallback).
// Outputs f32: [gelu 4*2048*512 | attention 4*2048*2048].

#define B_ 4
#define N_ 2048
#define F_ 512
#define ALPHA_ 0.2f
#define NEG_INF_ -9000000000000000.0f
#define EPS_LN_ 1e-5f

typedef __attribute__((ext_vector_type(8))) short bf16x8;
typedef __attribute__((ext_vector_type(4))) short bf16x4;
typedef __attribute__((ext_vector_type(4))) float f32x4;

// ---- workspace layout (bytes). Lifetimes:
//  hbf: conv->gemm1 | Wt: pre->gemm1 | el: conv->attn | Wht: gemm1->gemm0
//  attbf: attn->gemm0 | HP: gemm0->lngelu (overlays hbf+Wt+el, all dead by then)
#define HBF_OFF   0           // bf16 [8192][512]    (8388608)
#define WT_OFF    8388608     // bf16 [512][512]     (524288)
#define EL_OFF    8912896     // f32  [4][8192]      (131072)
#define HP_OFF    0           // f32  [8192][512]    (16777216) overlay
#define WHT_OFF   16777216    // bf16 [4][512][2048] (8388608)
#define ATTBF_OFF 25165824    // bf16 [4][2048][2048](33554432) -> ends 58720256
#define CANON_OFF 58720256    // f32 [1024]  (gamma 512 | beta 512)
#define SC_OFF    58724352    // f32 [16]
#define V_OFF     58724416    // f32 [4][512]
// peak ~58.73 MB

__device__ __forceinline__ float bf_as_f32(unsigned short u) {
    return __uint_as_float(((unsigned)u) << 16);
}
__device__ __forceinline__ float ldf(const void* p, long i, int isf32) {
    return isf32 ? ((const float*)p)[i] : bf_as_f32(((const unsigned short*)p)[i]);
}
__device__ __forceinline__ short f2bf(float f) {
    __hip_bfloat16 t = __float2bfloat16(f);
    return *reinterpret_cast<short*>(&t);
}
// Uniform per-thread dtype probe: f32 data read as bf16 shows random exponents (max >> 1e10).
// 64 shorts = 32 low-mantissa halves for f32 data -> P(miss) ~ 4e-7; verified f32 on this input.
__device__ __forceinline__ int detect_f32(const unsigned short* p) {
    float mx = 0.f;
    for (int i = 0; i < 64; ++i) {
        float x = fabsf(bf_as_f32(p[i]));
        if (x == x && x > mx) mx = x;
    }
    return mx > 1e10f;
}

#define GLL16(g, l) __builtin_amdgcn_global_load_lds( \
    (const __attribute__((address_space(1))) void*)(g), \
    (__attribute__((address_space(3))) void*)(l), 16, 0, 0)

// ---------- k_pre (273 blocks): [0,256) W-transpose | [256,272) v = W@a dots | [272] scalars ----------
__global__ __launch_bounds__(256) void k_pre(const unsigned short* __restrict__ hraw, const void* __restrict__ W,
                                             const void* alp, const void* arp, const void* aln, const void* arn,
                                             const void* rel, const void* arelp, const void* areln,
                                             const void* ll1, const void* lr1, const void* ll2, const void* lr2,
                                             const void* gam, const void* bet,
                                             __hip_bfloat16* __restrict__ Wt, float* __restrict__ v,
                                             float* __restrict__ canon, float* __restrict__ sc) {
    __shared__ float t[32][33];
    int fl = detect_f32(hraw);
    int bi = blockIdx.x, tid = threadIdx.x, lane = tid & 63, wid = tid >> 6;
    if (bi < 256) {
        // transpose W[k][o] -> Wt[o][k] bf16, 32x32 LDS tiles
        int k0 = (bi & 15) * 32, o0 = (bi >> 4) * 32;
        int tx = tid & 31, ty = tid >> 5;
#pragma unroll
        for (int r = 0; r < 4; ++r)
            t[ty + r * 8][tx] = ldf(W, (long)(k0 + ty + r * 8) * 512 + o0 + tx, fl);
        __syncthreads();
#pragma unroll
        for (int r = 0; r < 4; ++r)
            Wt[(o0 + ty + r * 8) * 512 + k0 + tx] = __float2bfloat16(t[tx][ty + r * 8]);
    } else if (bi < 272) {
        // v[0]=W[:, :256]@alp, v[1]=@arp, v[2]=W[:,256:]@aln, v[3]=@arn  (per k; no atomics)
        int k = (bi - 256) * 32 + (tid >> 3);
        int seg = tid & 7;
        int pos = seg < 4;
        int ob = (seg & 3) * 64 + (pos ? 0 : 256);
        const void* aL = pos ? alp : aln;
        const void* aR = pos ? arp : arn;
        float sL = 0.f, sR = 0.f;
        for (int e = 0; e < 64; ++e) {
            float w = ldf(W, (long)k * 512 + ob + e, fl);
            sL += w * ldf(aL, (ob & 255) + e, fl);
            sR += w * ldf(aR, (ob & 255) + e, fl);
        }
        sL += __shfl_xor(sL, 1); sL += __shfl_xor(sL, 2);
        sR += __shfl_xor(sR, 1); sR += __shfl_xor(sR, 2);
        if ((seg & 3) == 0) {
            int vb = pos ? 0 : 2;
            v[vb * 512 + k] = sL;
            v[(vb + 1) * 512 + k] = sR;
        }
    } else {
        // canon: gamma/beta; sc: lambda + 6 rel-dot scalars per sign
        canon[tid] = ldf(gam, tid, fl);
        canon[256 + tid] = ldf(gam, 256 + tid, fl);
        canon[512 + tid] = ldf(bet, tid, fl);
        canon[768 + tid] = ldf(bet, 256 + tid, fl);
        if (wid == 0) {
            float s1 = 0.f, s2 = 0.f;
            for (int k = lane; k < 256; k += 64) {
                s1 += ldf(ll1, k, fl) * ldf(lr1, k, fl);
                s2 += ldf(ll2, k, fl) * ldf(lr2, k, fl);
            }
            for (int off = 32; off; off >>= 1) { s1 += __shfl_down(s1, off); s2 += __shfl_down(s2, off); }
            if (lane == 0) {
                float lam_init = 0.8f - 0.6f * expf(-0.3f);
                sc[0] = expf(s1) - expf(s2) + lam_init;
            }
        } else if (wid == 1 && lane < 6) {
            float p = 0.f, n = 0.f;
            for (int d = 0; d < 10; ++d) {
                float rv = ldf(rel, lane * 10 + d, fl);
                p += rv * ldf(arelp, d, fl);
                n += rv * ldf(areln, d, fl);
            }
            sc[1 + lane] = p;
            sc[7 + lane] = n;
        }
    }
}

// ---------- k_conv: h -> bf16 (8/thread) + fused el row-dots (wave = 1 row) ----------
__global__ __launch_bounds__(256) void k_conv(const void* __restrict__ h, short* __restrict__ hbf,
                                              const float* __restrict__ v, float* __restrict__ el) {
    int fl = detect_f32((const unsigned short*)h);
    int tid = threadIdx.x, lane = tid & 63;
    long i = ((long)blockIdx.x * 256 + tid) * 8;
    int row = (int)(i >> 9);
    float f[8];
    if (fl) {
        const float4* p = (const float4*)((const float*)h + i);
        float4 a = p[0], b = p[1];
        f[0] = a.x; f[1] = a.y; f[2] = a.z; f[3] = a.w;
        f[4] = b.x; f[5] = b.y; f[6] = b.z; f[7] = b.w;
    } else {
        bf16x8 x = *(const bf16x8*)((const short*)h + i);
#pragma unroll
        for (int e = 0; e < 8; ++e) f[e] = bf_as_f32((unsigned short)x[e]);
    }
    bf16x8 vv;
#pragma unroll
    for (int e = 0; e < 8; ++e) vv[e] = f2bf(f[e]);
    *(bf16x8*)(hbf + i) = vv;
    const float* v0 = v + 0 * 512 + lane * 8;
    const float* v1 = v + 1 * 512 + lane * 8;
    const float* v2 = v + 2 * 512 + lane * 8;
    const float* v3 = v + 3 * 512 + lane * 8;
    float slp = 0.f, srp = 0.f, sln = 0.f, srn = 0.f;
#pragma unroll
    for (int e = 0; e < 8; ++e) {
        slp += f[e] * v0[e]; srp += f[e] * v1[e];
        sln += f[e] * v2[e]; srn += f[e] * v3[e];
    }
    for (int off = 32; off; off >>= 1) {
        slp += __shfl_xor(slp, off); srp += __shfl_xor(srp, off);
        sln += __shfl_xor(sln, off); srn += __shfl_xor(srn, off);
    }
    if (lane == 0) {
        el[row] = slp; el[8192 + row] = srp; el[16384 + row] = sln; el[24576 + row] = srn;
    }
}

// ---------- generic MFMA GEMM: BM=128 BN=64 BK=128, 4 waves (64x32 each), XOR-swizzled LDS ----
// TRANS_OUT=0: C f32 [M][N] row-major.  TRANS_OUT=1: C bf16 Wht[b][o][j] (transposed store).
template<int TRANS_OUT>
__global__ __launch_bounds__(256) void k_gemm(const short* __restrict__ A, const short* __restrict__ B,
                                              void* __restrict__ Cout, int K, int N,
                                              long aBatch, long bBatch, long cBatch) {
    __shared__ short SM[24576];         // As 128x128 (32KB) + Bs 64x128 (16KB)
    short* As = SM;
    short* Bs = SM + 16384;
    int tid = threadIdx.x, wid = tid >> 6, lane = tid & 63;
    int bm = blockIdx.x * 128, bn = blockIdx.y * 64, bz = blockIdx.z;
    const short* Ab = A + bz * aBatch + (long)bm * K;
    const short* Bb = B + bz * bBatch + (long)bn * K;
    f32x4 acc[4][2] = {};
    int wr = (wid >> 1) * 64, wc = (wid & 1) * 32;
    int l15 = lane & 15, lhi = lane >> 4;
    for (int k0 = 0; k0 < K; k0 += 128) {
        __syncthreads();
#pragma unroll
        for (int j = 0; j < 8; ++j) {       // A: 2048 16B-chunks, source pre-swizzled (rule 21)
            int q = tid + j * 256;
            int row = q >> 4, c = (q & 15) ^ (row & 7);
            GLL16(Ab + (long)row * K + k0 + c * 8, As + q * 8);
        }
#pragma unroll
        for (int j = 0; j < 4; ++j) {       // B: 1024 chunks
            int q = tid + j * 256;
            int row = q >> 4, c = (q & 15) ^ (row & 7);
            GLL16(Bb + (long)row * K + k0 + c * 8, Bs + q * 8);
        }
        __syncthreads();                    // compiler drains vmcnt before barrier
#pragma unroll
        for (int ks = 0; ks < 4; ++ks) {
            bf16x8 af[4], bq[2];
#pragma unroll
            for (int m = 0; m < 4; ++m) {
                int r = wr + m * 16 + l15;
                int c = (ks * 4 + lhi) ^ (r & 7);
                af[m] = *(const bf16x8*)&As[r * 128 + c * 8];
            }
#pragma unroll
            for (int n = 0; n < 2; ++n) {
                int r = wc + n * 16 + l15;
                int c = (ks * 4 + lhi) ^ (r & 7);
                bq[n] = *(const bf16x8*)&Bs[r * 128 + c * 8];
            }
#pragma unroll
            for (int m = 0; m < 4; ++m)
#pragma unroll
                for (int n = 0; n < 2; ++n)
                    acc[m][n] = __builtin_amdgcn_mfma_f32_16x16x32_bf16(af[m], bq[n], acc[m][n], 0, 0, 0);
        }
    }
    int rg = lhi * 4;
    if (TRANS_OUT == 0) {
        float* C = (float*)Cout + bz * cBatch;
#pragma unroll
        for (int m = 0; m < 4; ++m)
#pragma unroll
            for (int n = 0; n < 2; ++n)
#pragma unroll
                for (int r = 0; r < 4; ++r)
                    C[(long)(bm + wr + m * 16 + rg + r) * N + bn + wc + n * 16 + l15] = acc[m][n][r];
    } else {
        // transposed bf16 store via LDS bounce: T[64 o][128 j], pad 136 shorts
        __syncthreads();
        short* T = SM;
#pragma unroll
        for (int m = 0; m < 4; ++m)
#pragma unroll
            for (int n = 0; n < 2; ++n) {
                bf16x4 p;
#pragma unroll
                for (int r = 0; r < 4; ++r) p[r] = f2bf(acc[m][n][r]);
                int o = wc + n * 16 + l15;
                int jj = wr + m * 16 + rg;
                *(bf16x4*)&T[o * 136 + jj] = p;
            }
        __syncthreads();
        int b = bm >> 11, jb = bm & 2047;
        int o = tid >> 2, sg = tid & 3;
        short* Wg = (short*)Cout + ((long)b * 512 + bn + o) * 2048 + jb + sg * 32;
#pragma unroll
        for (int w2 = 0; w2 < 4; ++w2)
            *(bf16x8*)(Wg + w2 * 8) = *(bf16x8*)&T[o * 136 + sg * 32 + w2 * 8];
    }
}

// ---------- attention rows: dual softmax; f32 att -> d_out, bf16 att -> ws ----------
__global__ __launch_bounds__(256) void k_attn(const int* __restrict__ adj,
                                              const float* __restrict__ el, const float* __restrict__ sc,
                                              float* __restrict__ att_f32,
                                              __hip_bfloat16* __restrict__ att_bf) {
    __shared__ float s_rp[8], s_rn[8], s_lam[1];
    __shared__ float rmp[4], rmn[4], rsp[4], rsn[4];
    int tid = threadIdx.x, lane = tid & 63, wid = tid >> 6;
    if (tid < 6) { s_rp[tid] = sc[1 + tid]; s_rn[tid] = sc[7 + tid]; }
    if (tid == 6) s_lam[0] = sc[0];
    int m = blockIdx.x, b = m >> 11;
    float elp = el[m], eln = el[16384 + m];
    const float* erp = el + 8192 + b * 2048;
    const float* ern = el + 24576 + b * 2048;
    const int* adjr = adj + (long)m * 2048;
    __syncthreads();
    int j0 = tid * 8;
    int4 A0 = *(const int4*)(adjr + j0), A1 = *(const int4*)(adjr + j0 + 4);
    float4 P0 = *(const float4*)(erp + j0), P1 = *(const float4*)(erp + j0 + 4);
    float4 Q0 = *(const float4*)(ern + j0), Q1 = *(const float4*)(ern + j0 + 4);
    int aa[8] = {A0.x, A0.y, A0.z, A0.w, A1.x, A1.y, A1.z, A1.w};
    float rp[8] = {P0.x, P0.y, P0.z, P0.w, P1.x, P1.y, P1.z, P1.w};
    float rn[8] = {Q0.x, Q0.y, Q0.z, Q0.w, Q1.x, Q1.y, Q1.z, Q1.w};
    float sp[8], sn[8];
    float mp = NEG_INF_, mn = NEG_INF_;
#pragma unroll
    for (int e = 0; e < 8; ++e) {
        int a = aa[e];
        float ep = elp + rp[e] + s_rp[a];
        float en = eln + rn[e] + s_rn[a];
        ep = ep >= 0.f ? ep : ALPHA_ * ep;
        en = en >= 0.f ? en : ALPHA_ * en;
        sp[e] = a > 0 ? ep : NEG_INF_;
        sn[e] = a > 0 ? en : NEG_INF_;
        mp = fmaxf(mp, sp[e]); mn = fmaxf(mn, sn[e]);
    }
    for (int off = 32; off; off >>= 1) { mp = fmaxf(mp, __shfl_down(mp, off)); mn = fmaxf(mn, __shfl_down(mn, off)); }
    if (lane == 0) { rmp[wid] = mp; rmn[wid] = mn; }
    __syncthreads();
    mp = fmaxf(fmaxf(rmp[0], rmp[1]), fmaxf(rmp[2], rmp[3]));
    mn = fmaxf(fmaxf(rmn[0], rmn[1]), fmaxf(rmn[2], rmn[3]));
    float sump = 0.f, sumn = 0.f;
#pragma unroll
    for (int e = 0; e < 8; ++e) {
        sp[e] = __expf(sp[e] - mp);     // masked -> 0; all-masked row -> uniform (matches ref)
        sn[e] = __expf(sn[e] - mn);
        sump += sp[e]; sumn += sn[e];
    }
    for (int off = 32; off; off >>= 1) { sump += __shfl_down(sump, off); sumn += __shfl_down(sumn, off); }
    if (lane == 0) { rsp[wid] = sump; rsn[wid] = sumn; }
    __syncthreads();
    sump = rsp[0] + rsp[1] + rsp[2] + rsp[3];
    sumn = rsn[0] + rsn[1] + rsn[2] + rsn[3];
    float ip = 1.0f / sump, inn = 1.0f / sumn;
    float lam = s_lam[0];
    float vout[8];
    bf16x8 vb;
#pragma unroll
    for (int e = 0; e < 8; ++e) {
        vout[e] = sp[e] * ip - lam * sn[e] * inn;
        vb[e] = f2bf(vout[e]);
    }
    float* of = att_f32 + (long)m * 2048 + j0;
    *(float4*)(of)     = make_float4(vout[0], vout[1], vout[2], vout[3]);
    *(float4*)(of + 4) = make_float4(vout[4], vout[5], vout[6], vout[7]);
    *(bf16x8*)((short*)att_bf + (long)m * 2048 + j0) = vb;
}

// ---------- LayerNorm + gamma/beta + *(1-lam_init) + exact GELU -> f32 (wave = 1 row) ----
__global__ __launch_bounds__(256) void k_lngelu(const float* __restrict__ HP, const float* __restrict__ canon,
                                                float* __restrict__ out) {
    int wid = threadIdx.x >> 6, lane = threadIdx.x & 63;
    int m = blockIdx.x * 4 + wid;
    const float* Hr = HP + (long)m * 512 + lane * 8;
    float4 x0 = *(const float4*)(Hr), x1 = *(const float4*)(Hr + 4);
    float x[8] = {x0.x, x0.y, x0.z, x0.w, x1.x, x1.y, x1.z, x1.w};
    float s = 0.f, ss = 0.f;
#pragma unroll
    for (int e = 0; e < 8; ++e) { s += x[e]; ss += x[e] * x[e]; }
    for (int off = 32; off; off >>= 1) { s += __shfl_xor(s, off); ss += __shfl_xor(ss, off); }
    float mu = s * (1.0f / 512.0f);
    float var = ss * (1.0f / 512.0f) - mu * mu;
    float inv = rsqrtf(fmaxf(var, 0.0f) + EPS_LN_);
    float scale = 1.0f - (0.8f - 0.6f * expf(-0.3f));
    const float* g8 = canon + lane * 8;
    const float* b8 = canon + 512 + lane * 8;
    float o[8];
#pragma unroll
    for (int e = 0; e < 8; ++e) {
        float y = (x[e] - mu) * inv * g8[e] + b8[e];
        y *= scale;
        o[e] = 0.5f * y * (1.0f + erff(y * 0.70710678118654752f));
    }
    float* op = out + (long)m * 512 + lane * 8;
    *(float4*)(op)     = make_float4(o[0], o[1], o[2], o[3]);
    *(float4*)(op + 4) = make_float4(o[4], o[5], o[6], o[7]);
}

extern "C" void kernel_launch(void* const* d_in, const int* in_sizes, int n_in,
                              void* d_out, int out_size, void* d_ws, size_t ws_size,
                              hipStream_t stream) {
    const void* h   = d_in[0];
    const int*  adj = (const int*)d_in[1];
    const void* W   = d_in[2];

    char* ws = (char*)d_ws;
    short*          hbf   = (short*)(ws + HBF_OFF);
    __hip_bfloat16* Wt    = (__hip_bfloat16*)(ws + WT_OFF);
    float*          el    = (float*)(ws + EL_OFF);
    float*          HP    = (float*)(ws + HP_OFF);
    __hip_bfloat16* Wht   = (__hip_bfloat16*)(ws + WHT_OFF);
    __hip_bfloat16* attbf = (__hip_bfloat16*)(ws + ATTBF_OFF);
    float*          can   = (float*)(ws + CANON_OFF);
    float*          sc    = (float*)(ws + SC_OFF);
    float*          v     = (float*)(ws + V_OFF);

    float* out_gelu = (float*)d_out;
    float* out_att  = out_gelu + (size_t)B_ * N_ * F_;

    k_pre<<<273, 256, 0, stream>>>((const unsigned short*)h, W,
                                   d_in[3], d_in[4], d_in[5], d_in[6], d_in[7], d_in[8], d_in[9],
                                   d_in[10], d_in[11], d_in[12], d_in[13], d_in[14], d_in[15],
                                   Wt, v, can, sc);
    k_conv<<<2048, 256, 0, stream>>>(h, hbf, v, el);
    // Wh^T (bf16 [b][o][j]) = (hbf @ Wt^T) transposed-store : M=8192 K=512 N=512
    k_gemm<1><<<dim3(64, 8, 1), 256, 0, stream>>>(hbf, (const short*)Wt, Wht, 512, 512, 0, 0, 0);
    k_attn<<<8192, 256, 0, stream>>>(adj, el, sc, out_att, attbf);
    // h_prime = att @ Wh : per batch M=2048 K=2048 N=512 (HP overlays dead hbf/Wt/el)
    k_gemm<0><<<dim3(16, 8, 4), 256, 0, stream>>>((const short*)attbf, (const short*)Wht, HP, 2048, 512,
                                                  2048L * 2048, 512L * 2048, 2048L * 512);
    k_lngelu<<<2048, 256, 0, stream>>>(HP, can, out_gelu);
}

// Round 9
// 257.193 us; speedup vs baseline: 1.1185x; 1.0413x over previous
//
#include <hip/hip_runtime.h>
#include <hip/hip_bf16.h>

// B=4, N=2048, F=512, INTERNAL=256. adj int32. Inputs f32 (runtime-detected per-block, bf16 fallback).
// Outputs f32: [gelu 4*2048*512 | attention 4*2048*2048].

#define B_ 4
#define N_ 2048
#define F_ 512
#define ALPHA_ 0.2f
#define NEG_INF_ -9000000000000000.0f
#define EPS_LN_ 1e-5f

typedef __attribute__((ext_vector_type(8))) short bf16x8;
typedef __attribute__((ext_vector_type(4))) short bf16x4;
typedef __attribute__((ext_vector_type(4))) float f32x4;

// ---- workspace layout (bytes). Lifetimes:
//  hbf: pre->gemm1 | Wt: pre->gemm1 | el: gemm1->attn | Wht: gemm1->gemm0
//  attbf: attn->gemm0 | HP: gemm0->lngelu (overlays hbf+Wt+el, all dead by then)
#define HBF_OFF   0           // bf16 [8192][512]    (8388608)
#define WT_OFF    8388608     // bf16 [512][512]     (524288)
#define EL_OFF    8912896     // f32  [4][8192]      (131072)
#define HP_OFF    0           // f32  [8192][512]    (16777216) overlay
#define WHT_OFF   16777216    // bf16 [4][512][2048] (8388608)
#define ATTBF_OFF 25165824    // bf16 [4][2048][2048](33554432) -> ends 58720256
#define CANON_OFF 58720256    // f32 [2048]: gamma512|beta512|alp256|arp256|aln256|arn256
#define SC_OFF    58728448    // f32 [16]
// peak ~58.73 MB

__device__ __forceinline__ float bf_as_f32(unsigned short u) {
    return __uint_as_float(((unsigned)u) << 16);
}
__device__ __forceinline__ float ldf(const void* p, long i, int isf32) {
    return isf32 ? ((const float*)p)[i] : bf_as_f32(((const unsigned short*)p)[i]);
}
__device__ __forceinline__ short f2bf(float f) {
    __hip_bfloat16 t = __float2bfloat16(f);
    return *reinterpret_cast<short*>(&t);
}
// Uniform per-thread dtype probe: f32 data read as bf16 shows random exponents (max >> 1e10).
__device__ __forceinline__ int detect_f32(const unsigned short* p) {
    float mx = 0.f;
    for (int i = 0; i < 64; ++i) {
        float x = fabsf(bf_as_f32(p[i]));
        if (x == x && x > mx) mx = x;
    }
    return mx > 1e10f;
}

#define GLL16(g, l) __builtin_amdgcn_global_load_lds( \
    (const __attribute__((address_space(1))) void*)(g), \
    (__attribute__((address_space(3))) void*)(l), 16, 0, 0)

// ---------- k_pre (2321 blocks): [0,2048) h->bf16 conv | [2048,2304) W-transpose |
//            [2304,2320) zero el | [2320] scalars + canon ----------
__global__ __launch_bounds__(256) void k_pre(const void* __restrict__ h, const void* __restrict__ W,
                                             const void* alp, const void* arp, const void* aln, const void* arn,
                                             const void* rel, const void* arelp, const void* areln,
                                             const void* ll1, const void* lr1, const void* ll2, const void* lr2,
                                             const void* gam, const void* bet,
                                             short* __restrict__ hbf, __hip_bfloat16* __restrict__ Wt,
                                             float* __restrict__ el, float* __restrict__ canon,
                                             float* __restrict__ sc) {
    __shared__ float t[32][33];
    int fl = detect_f32((const unsigned short*)h);
    int bi = blockIdx.x, tid = threadIdx.x, lane = tid & 63, wid = tid >> 6;
    if (bi < 2048) {
        long i = ((long)bi * 256 + tid) * 8;
        bf16x8 vv;
        if (fl) {
            const float4* p = (const float4*)((const float*)h + i);
            float4 a = p[0], b = p[1];
            vv[0] = f2bf(a.x); vv[1] = f2bf(a.y); vv[2] = f2bf(a.z); vv[3] = f2bf(a.w);
            vv[4] = f2bf(b.x); vv[5] = f2bf(b.y); vv[6] = f2bf(b.z); vv[7] = f2bf(b.w);
        } else {
            vv = *(const bf16x8*)((const short*)h + i);
        }
        *(bf16x8*)(hbf + i) = vv;
    } else if (bi < 2304) {
        int b2 = bi - 2048;
        int k0 = (b2 & 15) * 32, o0 = (b2 >> 4) * 32;
        int tx = tid & 31, ty = tid >> 5;
#pragma unroll
        for (int r = 0; r < 4; ++r)
            t[ty + r * 8][tx] = ldf(W, (long)(k0 + ty + r * 8) * 512 + o0 + tx, fl);
        __syncthreads();
#pragma unroll
        for (int r = 0; r < 4; ++r)
            Wt[(o0 + ty + r * 8) * 512 + k0 + tx] = __float2bfloat16(t[tx][ty + r * 8]);
    } else if (bi < 2320) {
        int base = (bi - 2304) * 2048 + tid * 8;
        float4 z = make_float4(0.f, 0.f, 0.f, 0.f);
        *(float4*)(el + base) = z;
        *(float4*)(el + base + 4) = z;
    } else {
        canon[tid] = ldf(gam, tid, fl);
        canon[256 + tid] = ldf(gam, 256 + tid, fl);
        canon[512 + tid] = ldf(bet, tid, fl);
        canon[768 + tid] = ldf(bet, 256 + tid, fl);
        canon[1024 + tid] = ldf(alp, tid, fl);
        canon[1280 + tid] = ldf(arp, tid, fl);
        canon[1536 + tid] = ldf(aln, tid, fl);
        canon[1792 + tid] = ldf(arn, tid, fl);
        if (wid == 0) {
            float s1 = 0.f, s2 = 0.f;
            for (int k = lane; k < 256; k += 64) {
                s1 += ldf(ll1, k, fl) * ldf(lr1, k, fl);
                s2 += ldf(ll2, k, fl) * ldf(lr2, k, fl);
            }
            for (int off = 32; off; off >>= 1) { s1 += __shfl_down(s1, off); s2 += __shfl_down(s2, off); }
            if (lane == 0) {
                float lam_init = 0.8f - 0.6f * expf(-0.3f);
                sc[0] = expf(s1) - expf(s2) + lam_init;
            }
        } else if (wid == 1 && lane < 6) {
            float p = 0.f, n = 0.f;
            for (int d = 0; d < 10; ++d) {
                float rv = ldf(rel, lane * 10 + d, fl);
                p += rv * ldf(arelp, d, fl);
                n += rv * ldf(areln, d, fl);
            }
            sc[1 + lane] = p;
            sc[7 + lane] = n;
        }
    }
}

// ---------- generic MFMA GEMM: BM=128 BN=64 BK=128, single-buffer (round-6-proven structure),
//            4 waves (64x32 each), XOR-swizzled LDS. TRANS_OUT=0: C f32 [M][N].
//            TRANS_OUT=1: C bf16 Wht[b][o][j] transposed store + fused el dots. ----------
template<int TRANS_OUT>
__global__ __launch_bounds__(256) void k_gemm(const short* __restrict__ A, const short* __restrict__ B,
                                              void* __restrict__ Cout, int K, int N,
                                              long aBatch, long bBatch, long cBatch,
                                              const float* __restrict__ canon, float* __restrict__ el) {
    __shared__ short SM[24576];         // As 128x128 (32KB) + Bs 64x128 (16KB)
    short* As = SM;
    short* Bs = SM + 16384;
    int tid = threadIdx.x, wid = tid >> 6, lane = tid & 63;
    int bm = blockIdx.x * 128, bn = blockIdx.y * 64, bz = blockIdx.z;
    const short* Ab = A + bz * aBatch + (long)bm * K;
    const short* Bb = B + bz * bBatch + (long)bn * K;
    f32x4 acc[4][2] = {};
    int wr = (wid >> 1) * 64, wc = (wid & 1) * 32;
    int l15 = lane & 15, lhi = lane >> 4;
    for (int k0 = 0; k0 < K; k0 += 128) {
        __syncthreads();
#pragma unroll
        for (int j = 0; j < 8; ++j) {       // A: 2048 16B-chunks, source pre-swizzled (rule 21)
            int q = tid + j * 256;
            int row = q >> 4, c = (q & 15) ^ (row & 7);
            GLL16(Ab + (long)row * K + k0 + c * 8, As + q * 8);
        }
#pragma unroll
        for (int j = 0; j < 4; ++j) {       // B: 1024 chunks
            int q = tid + j * 256;
            int row = q >> 4, c = (q & 15) ^ (row & 7);
            GLL16(Bb + (long)row * K + k0 + c * 8, Bs + q * 8);
        }
        __syncthreads();                    // compiler drains vmcnt before barrier
#pragma unroll
        for (int ks = 0; ks < 4; ++ks) {
            bf16x8 af[4], bq[2];
#pragma unroll
            for (int m = 0; m < 4; ++m) {
                int r = wr + m * 16 + l15;
                int c = (ks * 4 + lhi) ^ (r & 7);
                af[m] = *(const bf16x8*)&As[r * 128 + c * 8];
            }
#pragma unroll
            for (int n = 0; n < 2; ++n) {
                int r = wc + n * 16 + l15;
                int c = (ks * 4 + lhi) ^ (r & 7);
                bq[n] = *(const bf16x8*)&Bs[r * 128 + c * 8];
            }
#pragma unroll
            for (int m = 0; m < 4; ++m)
#pragma unroll
                for (int n = 0; n < 2; ++n)
                    acc[m][n] = __builtin_amdgcn_mfma_f32_16x16x32_bf16(af[m], bq[n], acc[m][n], 0, 0, 0);
        }
    }
    int rg = lhi * 4;
    if (TRANS_OUT == 0) {
        float* C = (float*)Cout + bz * cBatch;
#pragma unroll
        for (int m = 0; m < 4; ++m)
#pragma unroll
            for (int n = 0; n < 2; ++n)
#pragma unroll
                for (int r = 0; r < 4; ++r)
                    C[(long)(bm + wr + m * 16 + rg + r) * N + bn + wc + n * 16 + l15] = acc[m][n][r];
    } else {
        // fused el dots: el[m] += sum_o Wh[m][o]*a[o] over this block's 64 o-cols
        int pos = bn < 256;
        int obase = (pos ? bn : bn - 256) + wc;
        const float* aL = canon + (pos ? 1024 : 1536);
        const float* aR = aL + 256;
        float aLv[2], aRv[2];
#pragma unroll
        for (int n = 0; n < 2; ++n) {
            int ol = obase + n * 16 + l15;
            aLv[n] = aL[ol]; aRv[n] = aR[ol];
        }
#pragma unroll
        for (int m = 0; m < 4; ++m)
#pragma unroll
            for (int r = 0; r < 4; ++r) {
                float sL = acc[m][0][r] * aLv[0] + acc[m][1][r] * aLv[1];
                float sR = acc[m][0][r] * aRv[0] + acc[m][1][r] * aRv[1];
#pragma unroll
                for (int off = 1; off < 16; off <<= 1) {
                    sL += __shfl_xor(sL, off); sR += __shfl_xor(sR, off);
                }
                if (l15 == 0) {
                    int rowg = bm + wr + m * 16 + rg + r;
                    atomicAdd(&el[(pos ? 0 : 2) * 8192 + rowg], sL);
                    atomicAdd(&el[(pos ? 1 : 3) * 8192 + rowg], sR);
                }
            }
        // transposed bf16 store via LDS bounce: T[64 o][128 j], pad 136 shorts
        __syncthreads();
        short* T = SM;
#pragma unroll
        for (int m = 0; m < 4; ++m)
#pragma unroll
            for (int n = 0; n < 2; ++n) {
                bf16x4 p;
#pragma unroll
                for (int r = 0; r < 4; ++r) p[r] = f2bf(acc[m][n][r]);
                int o = wc + n * 16 + l15;
                int jj = wr + m * 16 + rg;
                *(bf16x4*)&T[o * 136 + jj] = p;
            }
        __syncthreads();
        int b = bm >> 11, jb = bm & 2047;
        int o = tid >> 2, sg = tid & 3;
        short* Wg = (short*)Cout + ((long)b * 512 + bn + o) * 2048 + jb + sg * 32;
#pragma unroll
        for (int w2 = 0; w2 < 4; ++w2)
            *(bf16x8*)(Wg + w2 * 8) = *(bf16x8*)&T[o * 136 + sg * 32 + w2 * 8];
    }
}

// ---------- attention rows: dual softmax; f32 att -> d_out, bf16 att -> ws ----------
__global__ __launch_bounds__(256) void k_attn(const int* __restrict__ adj,
                                              const float* __restrict__ el, const float* __restrict__ sc,
                                              float* __restrict__ att_f32,
                                              __hip_bfloat16* __restrict__ att_bf) {
    __shared__ float s_rp[8], s_rn[8], s_lam[1];
    __shared__ float rmp[4], rmn[4], rsp[4], rsn[4];
    int tid = threadIdx.x, lane = tid & 63, wid = tid >> 6;
    if (tid < 6) { s_rp[tid] = sc[1 + tid]; s_rn[tid] = sc[7 + tid]; }
    if (tid == 6) s_lam[0] = sc[0];
    int m = blockIdx.x, b = m >> 11;
    float elp = el[m], eln = el[16384 + m];
    const float* erp = el + 8192 + b * 2048;
    const float* ern = el + 24576 + b * 2048;
    const int* adjr = adj + (long)m * 2048;
    __syncthreads();
    int j0 = tid * 8;
    int4 A0 = *(const int4*)(adjr + j0), A1 = *(const int4*)(adjr + j0 + 4);
    float4 P0 = *(const float4*)(erp + j0), P1 = *(const float4*)(erp + j0 + 4);
    float4 Q0 = *(const float4*)(ern + j0), Q1 = *(const float4*)(ern + j0 + 4);
    int aa[8] = {A0.x, A0.y, A0.z, A0.w, A1.x, A1.y, A1.z, A1.w};
    float rp[8] = {P0.x, P0.y, P0.z, P0.w, P1.x, P1.y, P1.z, P1.w};
    float rn[8] = {Q0.x, Q0.y, Q0.z, Q0.w, Q1.x, Q1.y, Q1.z, Q1.w};
    float sp[8], sn[8];
    float mp = NEG_INF_, mn = NEG_INF_;
#pragma unroll
    for (int e = 0; e < 8; ++e) {
        int a = aa[e];
        float ep = elp + rp[e] + s_rp[a];
        float en = eln + rn[e] + s_rn[a];
        ep = ep >= 0.f ? ep : ALPHA_ * ep;
        en = en >= 0.f ? en : ALPHA_ * en;
        sp[e] = a > 0 ? ep : NEG_INF_;
        sn[e] = a > 0 ? en : NEG_INF_;
        mp = fmaxf(mp, sp[e]); mn = fmaxf(mn, sn[e]);
    }
    for (int off = 32; off; off >>= 1) { mp = fmaxf(mp, __shfl_down(mp, off)); mn = fmaxf(mn, __shfl_down(mn, off)); }
    if (lane == 0) { rmp[wid] = mp; rmn[wid] = mn; }
    __syncthreads();
    mp = fmaxf(fmaxf(rmp[0], rmp[1]), fmaxf(rmp[2], rmp[3]));
    mn = fmaxf(fmaxf(rmn[0], rmn[1]), fmaxf(rmn[2], rmn[3]));
    float sump = 0.f, sumn = 0.f;
#pragma unroll
    for (int e = 0; e < 8; ++e) {
        sp[e] = __expf(sp[e] - mp);     // masked -> 0; all-masked row -> uniform (matches ref)
        sn[e] = __expf(sn[e] - mn);
        sump += sp[e]; sumn += sn[e];
    }
    for (int off = 32; off; off >>= 1) { sump += __shfl_down(sump, off); sumn += __shfl_down(sumn, off); }
    if (lane == 0) { rsp[wid] = sump; rsn[wid] = sumn; }
    __syncthreads();
    sump = rsp[0] + rsp[1] + rsp[2] + rsp[3];
    sumn = rsn[0] + rsn[1] + rsn[2] + rsn[3];
    float ip = 1.0f / sump, inn = 1.0f / sumn;
    float lam = s_lam[0];
    float vout[8];
    bf16x8 vb;
#pragma unroll
    for (int e = 0; e < 8; ++e) {
        vout[e] = sp[e] * ip - lam * sn[e] * inn;
        vb[e] = f2bf(vout[e]);
    }
    float* of = att_f32 + (long)m * 2048 + j0;
    *(float4*)(of)     = make_float4(vout[0], vout[1], vout[2], vout[3]);
    *(float4*)(of + 4) = make_float4(vout[4], vout[5], vout[6], vout[7]);
    *(bf16x8*)((short*)att_bf + (long)m * 2048 + j0) = vb;
}

// ---------- LayerNorm + gamma/beta + *(1-lam_init) + exact GELU -> f32 (wave = 1 row) ----
__global__ __launch_bounds__(256) void k_lngelu(const float* __restrict__ HP, const float* __restrict__ canon,
                                                float* __restrict__ out) {
    int wid = threadIdx.x >> 6, lane = threadIdx.x & 63;
    int m = blockIdx.x * 4 + wid;
    const float* Hr = HP + (long)m * 512 + lane * 8;
    float4 x0 = *(const float4*)(Hr), x1 = *(const float4*)(Hr + 4);
    float x[8] = {x0.x, x0.y, x0.z, x0.w, x1.x, x1.y, x1.z, x1.w};
    float s = 0.f, ss = 0.f;
#pragma unroll
    for (int e = 0; e < 8; ++e) { s += x[e]; ss += x[e] * x[e]; }
    for (int off = 32; off; off >>= 1) { s += __shfl_xor(s, off); ss += __shfl_xor(ss, off); }
    float mu = s * (1.0f / 512.0f);
    float var = ss * (1.0f / 512.0f) - mu * mu;
    float inv = rsqrtf(fmaxf(var, 0.0f) + EPS_LN_);
    float scale = 1.0f - (0.8f - 0.6f * expf(-0.3f));
    const float* g8 = canon + lane * 8;
    const float* b8 = canon + 512 + lane * 8;
    float o[8];
#pragma unroll
    for (int e = 0; e < 8; ++e) {
        float y = (x[e] - mu) * inv * g8[e] + b8[e];
        y *= scale;
        o[e] = 0.5f * y * (1.0f + erff(y * 0.70710678118654752f));
    }
    float* op = out + (long)m * 512 + lane * 8;
    *(float4*)(op)     = make_float4(o[0], o[1], o[2], o[3]);
    *(float4*)(op + 4) = make_float4(o[4], o[5], o[6], o[7]);
}

extern "C" void kernel_launch(void* const* d_in, const int* in_sizes, int n_in,
                              void* d_out, int out_size, void* d_ws, size_t ws_size,
                              hipStream_t stream) {
    const void* h   = d_in[0];
    const int*  adj = (const int*)d_in[1];
    const void* W   = d_in[2];

    char* ws = (char*)d_ws;
    short*          hbf   = (short*)(ws + HBF_OFF);
    __hip_bfloat16* Wt    = (__hip_bfloat16*)(ws + WT_OFF);
    float*          el    = (float*)(ws + EL_OFF);
    float*          HP    = (float*)(ws + HP_OFF);
    __hip_bfloat16* Wht   = (__hip_bfloat16*)(ws + WHT_OFF);
    __hip_bfloat16* attbf = (__hip_bfloat16*)(ws + ATTBF_OFF);
    float*          can   = (float*)(ws + CANON_OFF);
    float*          sc    = (float*)(ws + SC_OFF);

    float* out_gelu = (float*)d_out;
    float* out_att  = out_gelu + (size_t)B_ * N_ * F_;

    k_pre<<<2321, 256, 0, stream>>>(h, W,
                                    d_in[3], d_in[4], d_in[5], d_in[6], d_in[7], d_in[8], d_in[9],
                                    d_in[10], d_in[11], d_in[12], d_in[13], d_in[14], d_in[15],
                                    hbf, Wt, el, can, sc);
    // Wh^T (bf16 [b][o][j]) = (hbf @ Wt^T) transposed-store + fused el : M=8192 K=512 N=512
    k_gemm<1><<<dim3(64, 8, 1), 256, 0, stream>>>(hbf, (const short*)Wt, Wht, 512, 512, 0, 0, 0, can, el);
    k_attn<<<8192, 256, 0, stream>>>(adj, el, sc, out_att, attbf);
    // h_prime = att @ Wh : per batch M=2048 K=2048 N=512 (HP overlays dead hbf/Wt/el)
    k_gemm<0><<<dim3(16, 8, 4), 256, 0, stream>>>((const short*)attbf, (const short*)Wht, HP, 2048, 512,
                                                  2048L * 2048, 512L * 2048, 2048L * 512, can, el);
    k_lngelu<<<2048, 256, 0, stream>>>(HP, can, out_gelu);
}